// Round 1
// baseline (812.060 us; speedup 1.0000x reference)
//
#include <hip/hip_runtime.h>
#include <hip/hip_bf16.h>
#include <stdint.h>

// AR(12) rollout: 12 sequential GEMMs of [B=128 x K=24576] x [K x N=2048].
// bf16 hi/lo split (3 MFMA products) for fp32-grade accuracy on matrix cores.

typedef __bf16 bf16x8 __attribute__((ext_vector_type(8)));
typedef float  f32x4  __attribute__((ext_vector_type(4)));

#define B_ 128
#define N_ 2048
#define P_ 12
#define K_ (P_*N_)          // 24576
#define KSPLIT 16
#define KCH (K_/KSPLIT)     // 1536
#define NITER (KCH/32)      // 48 k-iterations of BK=32

#define WPK_BYTES   ((size_t)P_*N_*N_*2)       // 100,663,296 per array (hi or lo)
#define H_SLOT_BYTES ((size_t)B_*N_*2)         // 524,288 bytes per window slot
#define H_BYTES     (23*H_SLOT_BYTES)          // 12,058,624
#define PART_BYTES  ((size_t)KSPLIT*B_*N_*4)   // 16,777,216
#define WS_NEEDED   (2*WPK_BYTES + 2*H_BYTES + PART_BYTES)   // ~242 MB

__device__ __forceinline__ unsigned short bf_hi(float f) {
    uint32_t u = __float_as_uint(f);
    return (unsigned short)((u + 0x7FFFu + ((u >> 16) & 1u)) >> 16);   // RNE
}
__device__ __forceinline__ float bf_f(unsigned short h) {
    return __uint_as_float(((uint32_t)h) << 16);
}

union U16x8 { unsigned short u[8]; uint4 q; };

// Window slot layout: [slot][kblk=k/32][b=0..127][k%32] bf16, with the T2 XOR
// swizzle pre-applied inside each 128x32 tile (8 KB): byte = (b*64 + (k&31)*2) ^ ((b&7)<<4).
// This makes the GEMM's A-staging a LINEAR copy (global_load_lds-able) and the
// per-fragment ds_read_b128 conflict-free.
__device__ __forceinline__ uint32_t h_off(int slot, int b, int k) {
    uint32_t t = (uint32_t)((b << 6) + ((k & 31) << 1)) ^ (uint32_t)((b & 7) << 4);
    return (uint32_t)slot * (uint32_t)H_SLOT_BYTES + (uint32_t)(k >> 5) * (B_ * 64) + t;
}

// ---------------- prep: W [12][2048(j)][2048(k)] fp32 -> packed bf16 hi/lo ----------------
// Packed B layout: Wpk[(kg>>3)][j][kg&7] with kg = i*2048+k, 16B per (kgblk,j).
__global__ void prep_w(const float* __restrict__ W, char* __restrict__ Wph, char* __restrict__ Wpl) {
    __shared__ float tile[64][68];   // +4 pad
    int id = blockIdx.x;
    int i  = id >> 10;          // 0..11
    int rem = id & 1023;
    int jt = rem >> 5, kt = rem & 31;
    int j0 = jt * 64, k0 = kt * 64;
    int t = threadIdx.x;
    #pragma unroll
    for (int pass = 0; pass < 4; ++pass) {          // coalesced fp32 reads along k
        int jl = pass * 16 + (t >> 4);
        int kq = (t & 15) * 4;
        float4 v = *(const float4*)(W + ((size_t)i * N_ + (j0 + jl)) * N_ + k0 + kq);
        tile[jl][kq + 0] = v.x; tile[jl][kq + 1] = v.y;
        tile[jl][kq + 2] = v.z; tile[jl][kq + 3] = v.w;
    }
    __syncthreads();
    #pragma unroll
    for (int pass = 0; pass < 2; ++pass) {          // coalesced 16B writes along j
        int itx = pass * 256 + t;
        int jl = itx & 63, kb = itx >> 6;           // kb 0..7
        U16x8 hi, lo;
        #pragma unroll
        for (int q = 0; q < 8; ++q) {
            float f = tile[jl][kb * 8 + q];
            unsigned short h = bf_hi(f);
            hi.u[q] = h;
            lo.u[q] = bf_hi(f - bf_f(h));
        }
        size_t kgblk = (size_t)i * 256 + (size_t)kt * 8 + kb;
        size_t off = (kgblk * N_ + (size_t)(j0 + jl)) * 16;
        *(uint4*)(Wph + off) = hi.q;
        *(uint4*)(Wpl + off) = lo.q;
    }
}

// ---------------- prep: x [128][2048][1][12] fp32 -> window slots 0..11 ----------------
__global__ void prep_x(const float* __restrict__ x, char* __restrict__ Hhi, char* __restrict__ Hlo) {
    int tid = blockIdx.x * 256 + threadIdx.x;   // 32768 threads: (b, n-octet)
    int b = tid >> 8;
    int n0 = (tid & 255) << 3;
    const float4* s4 = (const float4*)(x + ((size_t)b * N_ + n0) * P_);  // 96 consecutive floats
    float4 tmp[24];
    #pragma unroll
    for (int i2 = 0; i2 < 24; ++i2) tmp[i2] = s4[i2];
    #pragma unroll
    for (int p = 0; p < 12; ++p) {
        U16x8 hi, lo;
        #pragma unroll
        for (int q = 0; q < 8; ++q) {
            int fi = q * 12 + p;                 // compile-time constant
            float4 blk = tmp[fi >> 2];
            float f = ((fi & 3) == 0) ? blk.x : ((fi & 3) == 1) ? blk.y : ((fi & 3) == 2) ? blk.z : blk.w;
            unsigned short h = bf_hi(f);
            hi.u[q] = h;
            lo.u[q] = bf_hi(f - bf_f(h));
        }
        uint32_t off = h_off(p, b, n0);
        *(uint4*)(Hhi + off) = hi.q;
        *(uint4*)(Hlo + off) = lo.q;
    }
}

// ---------------- per-step GEMM: partial[ks][b][j] = A_chunk x W_chunk ----------------
// grid 256 = 16 ks-splits x 16 n-tiles; 8 waves; wave = 128(M) x 16(N) output.
__global__ __launch_bounds__(512) void gemm_step(
        const char* __restrict__ Wph, const char* __restrict__ Wpl,
        const char* __restrict__ Hhi, const char* __restrict__ Hlo,
        float* __restrict__ partial, int t)
{
    __shared__ alignas(16) char ldsA[2][2][8192];   // [buf][hi/lo][128x32 bf16 tile]
    const int tid  = threadIdx.x;
    const int lane = tid & 63;
    const int wv   = tid >> 6;
    const int bid  = blockIdx.x;
    const int ks    = bid >> 4;
    const int ntile = bid & 15;
    const int jcol = (ntile << 7) + (wv << 4) + (lane & 15);
    const int kq   = lane >> 4;                     // k-octet 0..3
    // swizzled A-fragment byte offset inside an 8KB tile (f adds +1024/row-set)
    const uint32_t aoff = (uint32_t)((((lane & 15) << 6) + (kq << 4)) ^ ((lane & 7) << 4));
    const int ksbase = ks * KCH;
    const size_t bcol16 = (size_t)jcol * 16;

    auto stage = [&](int buf, int it) {             // linear global->LDS, width 16
        int kg = ksbase + (it << 5);
        int slot = t + (kg >> 11);
        uint32_t src = (uint32_t)slot * (uint32_t)H_SLOT_BYTES
                     + (uint32_t)(((kg & 2047) >> 5)) * 8192u
                     + (uint32_t)((wv << 10) + (lane << 4));
        __builtin_amdgcn_global_load_lds(
            (const __attribute__((address_space(1))) void*)(Hhi + src),
            (__attribute__((address_space(3))) void*)&ldsA[buf][0][wv << 10], 16, 0, 0);
        __builtin_amdgcn_global_load_lds(
            (const __attribute__((address_space(1))) void*)(Hlo + src),
            (__attribute__((address_space(3))) void*)&ldsA[buf][1][wv << 10], 16, 0, 0);
    };
    auto loadB = [&](int it, bf16x8& bh, bf16x8& bl) {
        size_t o = ((size_t)(ks * 192 + it * 4 + kq) << 15) + bcol16;  // kgblk*2048*16 + j*16
        bh = *(const bf16x8*)(Wph + o);
        bl = *(const bf16x8*)(Wpl + o);
    };

    f32x4 acc[8];
    #pragma unroll
    for (int f = 0; f < 8; ++f) acc[f] = (f32x4){0.f, 0.f, 0.f, 0.f};

    bf16x8 bh0, bl0, bh1, bl1;
    stage(0, 0);
    loadB(0, bh0, bl0);
    __syncthreads();                                // compiler drains vmcnt before barrier

    auto compute = [&](const char* lb, bf16x8 bh, bf16x8 bl) {
        #pragma unroll
        for (int f = 0; f < 8; ++f) {
            bf16x8 ah = *(const bf16x8*)(lb + aoff + (f << 10));
            bf16x8 al = *(const bf16x8*)(lb + 8192 + aoff + (f << 10));
            acc[f] = __builtin_amdgcn_mfma_f32_16x16x32_bf16(ah, bh, acc[f], 0, 0, 0);
            acc[f] = __builtin_amdgcn_mfma_f32_16x16x32_bf16(al, bh, acc[f], 0, 0, 0);
            acc[f] = __builtin_amdgcn_mfma_f32_16x16x32_bf16(ah, bl, acc[f], 0, 0, 0);
        }
    };

    for (int it = 0; it < NITER; it += 2) {
        stage(1, it + 1);                           // prefetch next tile (other buffer)
        loadB(it + 1, bh1, bl1);
        compute(&ldsA[0][0][0], bh0, bl0);
        __syncthreads();
        if (it + 2 < NITER) { stage(0, it + 2); loadB(it + 2, bh0, bl0); }
        compute(&ldsA[1][0][0], bh1, bl1);
        __syncthreads();
    }

    // C/D layout (m89-verified): col = lane&15, row = (lane>>4)*4 + reg
    float* pb = partial + (size_t)ks * B_ * N_ + jcol;
    const int r0 = (lane >> 4) << 2;
    #pragma unroll
    for (int f = 0; f < 8; ++f) {
        #pragma unroll
        for (int r = 0; r < 4; ++r)
            pb[(size_t)(f * 16 + r0 + r) * N_] = acc[f][r];
    }
}

// ---------------- reduce 16 partials -> y; emit output column + next window slot ----------------
__global__ void reduce_step(const float* __restrict__ partial, float* __restrict__ out,
                            char* __restrict__ Hhi, char* __restrict__ Hlo, int t)
{
    int tid = blockIdx.x * 256 + threadIdx.x;   // 32768 threads: (b, n-octet)
    int b = tid >> 8;
    int n0 = (tid & 255) << 3;
    float s[8] = {0.f, 0.f, 0.f, 0.f, 0.f, 0.f, 0.f, 0.f};
    #pragma unroll
    for (int ksI = 0; ksI < KSPLIT; ++ksI) {
        const float4* p = (const float4*)(partial + ((size_t)ksI * B_ + b) * N_ + n0);
        float4 a = p[0], c = p[1];
        s[0] += a.x; s[1] += a.y; s[2] += a.z; s[3] += a.w;
        s[4] += c.x; s[5] += c.y; s[6] += c.z; s[7] += c.w;
    }
    float* ob = out + ((size_t)b * N_ + n0) * P_ + t;
    #pragma unroll
    for (int q = 0; q < 8; ++q) ob[q * P_] = s[q];
    if (t < 11) {                                // y_12 never re-enters the window
        U16x8 hi, lo;
        #pragma unroll
        for (int q = 0; q < 8; ++q) {
            unsigned short h = bf_hi(s[q]);
            hi.u[q] = h;
            lo.u[q] = bf_hi(s[q] - bf_f(h));
        }
        uint32_t off = h_off(12 + t, b, n0);
        *(uint4*)(Hhi + off) = hi.q;
        *(uint4*)(Hlo + off) = lo.q;
    }
}

// ---------------- insurance: naive fp32 path if workspace is too small ----------------
__global__ void naive_step(const float* __restrict__ x, const float* __restrict__ W,
                           float* __restrict__ out, int t)
{
    int tid = blockIdx.x * 256 + threadIdx.x;   // 262144 threads: (b, j)
    int b = tid >> 11;
    int j = tid & (N_ - 1);
    float acc = 0.f;
    for (int i = 0; i < 12; ++i) {
        int g = t + i;
        const float* src = (g < 12) ? (x   + (size_t)b * (N_ * 12) + g)
                                    : (out + (size_t)b * (N_ * 12) + (g - 12));
        const float* wr = W + ((size_t)i * N_ + j) * N_;
        for (int k = 0; k < N_; ++k)
            acc += wr[k] * src[(size_t)k * 12];
    }
    out[((size_t)b * N_ + j) * 12 + t] = acc;
}

extern "C" void kernel_launch(void* const* d_in, const int* in_sizes, int n_in,
                              void* d_out, int out_size, void* d_ws, size_t ws_size,
                              hipStream_t stream)
{
    const float* x = (const float*)d_in[0];
    const float* W = (const float*)d_in[1];
    float* out = (float*)d_out;

    if (ws_size < WS_NEEDED) {                  // fallback: correct but slow
        for (int t = 0; t < 12; ++t)
            naive_step<<<1024, 256, 0, stream>>>(x, W, out, t);
        return;
    }

    char* ws  = (char*)d_ws;
    char* Wph = ws;
    char* Wpl = Wph + WPK_BYTES;
    char* Hhi = Wpl + WPK_BYTES;
    char* Hlo = Hhi + H_BYTES;
    float* partial = (float*)(Hlo + H_BYTES);

    prep_w<<<12288, 256, 0, stream>>>(W, Wph, Wpl);
    prep_x<<<128, 256, 0, stream>>>(x, Hhi, Hlo);
    for (int t = 0; t < 12; ++t) {
        gemm_step<<<256, 512, 0, stream>>>(Wph, Wpl, Hhi, Hlo, partial, t);
        reduce_step<<<128, 256, 0, stream>>>(partial, out, Hhi, Hlo, t);
    }
}

// Round 2
// 578.277 us; speedup vs baseline: 1.4043x; 1.4043x over previous
//
#include <hip/hip_runtime.h>
#include <hip/hip_bf16.h>
#include <stdint.h>

// AR(12) rollout: 12 sequential GEMMs of [B=128 x K=24576] x [K x N=2048].
// A (window) kept bf16 hi/lo split; W in bf16 hi only -> 2 MFMA products.
// Accuracy budget: W-quant adds ~9e18 abs err (max stat over 262K outputs),
// measured base error 4.6e18, threshold 2.45e19 -> ~2x margin.

typedef __bf16 bf16x8 __attribute__((ext_vector_type(8)));
typedef float  f32x4  __attribute__((ext_vector_type(4)));

#define B_ 128
#define N_ 2048
#define P_ 12
#define K_ (P_*N_)          // 24576
#define KSPLIT 48
#define KCH (K_/KSPLIT)     // 512
#define NITER (KCH/32)      // 16 k-iterations of BK=32

#define WPK_BYTES   ((size_t)P_*N_*N_*2)       // 100,663,296 (hi only)
#define H_SLOT_BYTES ((size_t)B_*N_*2)         // 524,288 per window slot
#define H_BYTES     (23*H_SLOT_BYTES)          // 12,058,624
#define PART_BYTES  ((size_t)KSPLIT*B_*N_*4)   // 50,331,648
#define WS_NEEDED   (WPK_BYTES + 2*H_BYTES + PART_BYTES)   // ~176 MB

__device__ __forceinline__ unsigned short bf_hi(float f) {
    uint32_t u = __float_as_uint(f);
    return (unsigned short)((u + 0x7FFFu + ((u >> 16) & 1u)) >> 16);   // RNE
}
__device__ __forceinline__ float bf_f(unsigned short h) {
    return __uint_as_float(((uint32_t)h) << 16);
}

union U16x8 { unsigned short u[8]; uint4 q; };

// Window slot layout: [slot][kblk=k/32][b=0..127][k%32] bf16, T2 XOR swizzle
// pre-applied per 128x32 tile: byte = (b*64 + (k&31)*2) ^ ((b&7)<<4).
// Linear global_load_lds staging + conflict-free ds_read_b128 fragments.
__device__ __forceinline__ uint32_t h_off(int slot, int b, int k) {
    uint32_t t = (uint32_t)((b << 6) + ((k & 31) << 1)) ^ (uint32_t)((b & 7) << 4);
    return (uint32_t)slot * (uint32_t)H_SLOT_BYTES + (uint32_t)(k >> 5) * (B_ * 64) + t;
}

// ---------------- prep: W [12][2048(j)][2048(k)] fp32 -> packed bf16 hi ----------------
// Packed B layout: Wph[(kg>>3)][j][kg&7] with kg = i*2048+k, 16B per (kgblk,j).
__global__ void prep_w(const float* __restrict__ W, char* __restrict__ Wph) {
    __shared__ float tile[64][68];   // +4 pad
    int id = blockIdx.x;
    int i  = id >> 10;          // 0..11
    int rem = id & 1023;
    int jt = rem >> 5, kt = rem & 31;
    int j0 = jt * 64, k0 = kt * 64;
    int t = threadIdx.x;
    #pragma unroll
    for (int pass = 0; pass < 4; ++pass) {          // coalesced fp32 reads along k
        int jl = pass * 16 + (t >> 4);
        int kq = (t & 15) * 4;
        float4 v = *(const float4*)(W + ((size_t)i * N_ + (j0 + jl)) * N_ + k0 + kq);
        tile[jl][kq + 0] = v.x; tile[jl][kq + 1] = v.y;
        tile[jl][kq + 2] = v.z; tile[jl][kq + 3] = v.w;
    }
    __syncthreads();
    #pragma unroll
    for (int pass = 0; pass < 2; ++pass) {          // coalesced 16B writes along j
        int itx = pass * 256 + t;
        int jl = itx & 63, kb = itx >> 6;           // kb 0..7
        U16x8 hi;
        #pragma unroll
        for (int q = 0; q < 8; ++q) hi.u[q] = bf_hi(tile[jl][kb * 8 + q]);
        size_t kgblk = (size_t)i * 256 + (size_t)kt * 8 + kb;
        size_t off = (kgblk * N_ + (size_t)(j0 + jl)) * 16;
        *(uint4*)(Wph + off) = hi.q;
    }
}

// ---------------- prep: x [128][2048][1][12] fp32 -> window slots 0..11 ----------------
__global__ void prep_x(const float* __restrict__ x, char* __restrict__ Hhi, char* __restrict__ Hlo) {
    int tid = blockIdx.x * 256 + threadIdx.x;   // 32768 threads: (b, n-octet)
    int b = tid >> 8;
    int n0 = (tid & 255) << 3;
    const float4* s4 = (const float4*)(x + ((size_t)b * N_ + n0) * P_);  // 96 consecutive floats
    float4 tmp[24];
    #pragma unroll
    for (int i2 = 0; i2 < 24; ++i2) tmp[i2] = s4[i2];
    #pragma unroll
    for (int p = 0; p < 12; ++p) {
        U16x8 hi, lo;
        #pragma unroll
        for (int q = 0; q < 8; ++q) {
            int fi = q * 12 + p;                 // compile-time constant
            float4 blk = tmp[fi >> 2];
            float f = ((fi & 3) == 0) ? blk.x : ((fi & 3) == 1) ? blk.y : ((fi & 3) == 2) ? blk.z : blk.w;
            unsigned short h = bf_hi(f);
            hi.u[q] = h;
            lo.u[q] = bf_hi(f - bf_f(h));
        }
        uint32_t off = h_off(p, b, n0);
        *(uint4*)(Hhi + off) = hi.q;
        *(uint4*)(Hlo + off) = lo.q;
    }
}

// ---------------- per-step GEMM: partial[ks][b][j] = A_chunk x W_chunk ----------------
// grid 768 = 16 (m,n)-tiles x 48 ks ; bid%8 == ks%8 -> A-slice sharers on one XCD.
// 4 waves/block, wave tile 64(M) x 64(N); block tile 64(M: mtile half) x 256(N).
__global__ __launch_bounds__(256, 3) void gemm_step(
        const char* __restrict__ Wph,
        const char* __restrict__ Hhi, const char* __restrict__ Hlo,
        float* __restrict__ partial, int t)
{
    __shared__ alignas(16) char ldsA[2][2][4096];   // [buf][hi/lo][64x32 bf16 tile]
    const int tid  = threadIdx.x;
    const int lane = tid & 63;
    const int wv   = tid >> 6;                      // 0..3
    const int bid  = blockIdx.x;
    const int ks    = bid % KSPLIT;
    const int nm    = bid / KSPLIT;                 // 0..15
    const int ntile = nm & 7;
    const int mtile = nm >> 3;
    const int jcol = (ntile << 8) + (wv << 6) + (lane & 15);   // + n*16 per fragment
    const int ko   = lane >> 4;                     // k-octet 0..3
    // swizzled A-fragment byte offset inside a 4KB 64x32 tile (m adds +1024)
    const uint32_t aoff = (uint32_t)((((lane & 15) << 6) + (ko << 4)) ^ ((lane & 7) << 4));
    const int kbase = ks * KCH;

    auto stage = [&](int buf, int it) {             // linear global->LDS, width 16
        int kg = kbase + (it << 5);
        int slot = t + (kg >> 11);
        uint32_t src = (uint32_t)slot * (uint32_t)H_SLOT_BYTES
                     + (uint32_t)((kg & 2047) >> 5) * 8192u
                     + (uint32_t)(mtile << 12)
                     + (uint32_t)((wv << 10) + (lane << 4));
        __builtin_amdgcn_global_load_lds(
            (const __attribute__((address_space(1))) void*)(Hhi + src),
            (__attribute__((address_space(3))) void*)&ldsA[buf][0][wv << 10], 16, 0, 0);
        __builtin_amdgcn_global_load_lds(
            (const __attribute__((address_space(1))) void*)(Hlo + src),
            (__attribute__((address_space(3))) void*)&ldsA[buf][1][wv << 10], 16, 0, 0);
    };
    auto loadB = [&](int it, bf16x8* bh) {
        #pragma unroll
        for (int n = 0; n < 4; ++n) {
            size_t kgblk = (size_t)(ks * (KCH / 8) + it * 4 + ko);
            size_t o = (kgblk * N_ + (size_t)(jcol + n * 16)) * 16;
            bh[n] = *(const bf16x8*)(Wph + o);
        }
    };

    f32x4 acc[4][4];
    #pragma unroll
    for (int m = 0; m < 4; ++m)
        #pragma unroll
        for (int n = 0; n < 4; ++n) acc[m][n] = (f32x4){0.f, 0.f, 0.f, 0.f};

    bf16x8 bh0[4], bh1[4];
    stage(0, 0);
    loadB(0, bh0);
    __syncthreads();

    auto compute = [&](const char* lb, const bf16x8* bh) {
        #pragma unroll
        for (int m = 0; m < 4; ++m) {
            bf16x8 ah = *(const bf16x8*)(lb + aoff + (m << 10));
            bf16x8 al = *(const bf16x8*)(lb + 4096 + aoff + (m << 10));
            #pragma unroll
            for (int n = 0; n < 4; ++n) {
                acc[m][n] = __builtin_amdgcn_mfma_f32_16x16x32_bf16(ah, bh[n], acc[m][n], 0, 0, 0);
                acc[m][n] = __builtin_amdgcn_mfma_f32_16x16x32_bf16(al, bh[n], acc[m][n], 0, 0, 0);
            }
        }
    };

    for (int it = 0; it < NITER; it += 2) {
        stage(1, it + 1);                           // prefetch next tile (other buffer)
        loadB(it + 1, bh1);
        compute(&ldsA[0][0][0], bh0);
        __syncthreads();
        if (it + 2 < NITER) { stage(0, it + 2); loadB(it + 2, bh0); }
        compute(&ldsA[1][0][0], bh1);
        __syncthreads();
    }

    // C/D layout (verified R0): col = lane&15, row = (lane>>4)*4 + reg
    const int r0 = (lane >> 4) << 2;
    float* pb = partial + ((size_t)ks * B_ + (mtile << 6) + r0) * N_ + jcol;
    #pragma unroll
    for (int m = 0; m < 4; ++m)
        #pragma unroll
        for (int n = 0; n < 4; ++n)
            #pragma unroll
            for (int r = 0; r < 4; ++r)
                pb[(size_t)(m * 16 + r) * N_ + n * 16] = acc[m][n][r];
}

// ---------------- reduce 48 partials -> y; emit output column + next window slot ----------------
__global__ void reduce_step(const float* __restrict__ partial, float* __restrict__ out,
                            char* __restrict__ Hhi, char* __restrict__ Hlo, int t)
{
    int tid = blockIdx.x * 256 + threadIdx.x;   // 32768 threads: (b, n-octet)
    int b = tid >> 8;
    int n0 = (tid & 255) << 3;
    float s[8] = {0.f, 0.f, 0.f, 0.f, 0.f, 0.f, 0.f, 0.f};
    #pragma unroll 4
    for (int ksI = 0; ksI < KSPLIT; ++ksI) {
        const float4* p = (const float4*)(partial + ((size_t)ksI * B_ + b) * N_ + n0);
        float4 a = p[0], c = p[1];
        s[0] += a.x; s[1] += a.y; s[2] += a.z; s[3] += a.w;
        s[4] += c.x; s[5] += c.y; s[6] += c.z; s[7] += c.w;
    }
    float* ob = out + ((size_t)b * N_ + n0) * P_ + t;
    #pragma unroll
    for (int q = 0; q < 8; ++q) ob[q * P_] = s[q];
    if (t < 11) {                                // y_12 never re-enters the window
        U16x8 hi, lo;
        #pragma unroll
        for (int q = 0; q < 8; ++q) {
            unsigned short h = bf_hi(s[q]);
            hi.u[q] = h;
            lo.u[q] = bf_hi(s[q] - bf_f(h));
        }
        uint32_t off = h_off(12 + t, b, n0);
        *(uint4*)(Hhi + off) = hi.q;
        *(uint4*)(Hlo + off) = lo.q;
    }
}

// ---------------- insurance: naive fp32 path if workspace is too small ----------------
__global__ void naive_step(const float* __restrict__ x, const float* __restrict__ W,
                           float* __restrict__ out, int t)
{
    int tid = blockIdx.x * 256 + threadIdx.x;   // 262144 threads: (b, j)
    int b = tid >> 11;
    int j = tid & (N_ - 1);
    float acc = 0.f;
    for (int i = 0; i < 12; ++i) {
        int g = t + i;
        const float* src = (g < 12) ? (x   + (size_t)b * (N_ * 12) + g)
                                    : (out + (size_t)b * (N_ * 12) + (g - 12));
        const float* wr = W + ((size_t)i * N_ + j) * N_;
        for (int k = 0; k < N_; ++k)
            acc += wr[k] * src[(size_t)k * 12];
    }
    out[((size_t)b * N_ + j) * 12 + t] = acc;
}

extern "C" void kernel_launch(void* const* d_in, const int* in_sizes, int n_in,
                              void* d_out, int out_size, void* d_ws, size_t ws_size,
                              hipStream_t stream)
{
    const float* x = (const float*)d_in[0];
    const float* W = (const float*)d_in[1];
    float* out = (float*)d_out;

    if (ws_size < WS_NEEDED) {                  // fallback: correct but slow
        for (int t = 0; t < 12; ++t)
            naive_step<<<1024, 256, 0, stream>>>(x, W, out, t);
        return;
    }

    char* ws  = (char*)d_ws;
    char* Wph = ws;
    char* Hhi = Wph + WPK_BYTES;
    char* Hlo = Hhi + H_BYTES;
    float* partial = (float*)(Hlo + H_BYTES);

    prep_w<<<12288, 256, 0, stream>>>(W, Wph);
    prep_x<<<128, 256, 0, stream>>>(x, Hhi, Hlo);
    for (int t = 0; t < 12; ++t) {
        gemm_step<<<768, 256, 0, stream>>>(Wph, Hhi, Hlo, partial, t);
        reduce_step<<<128, 256, 0, stream>>>(partial, out, Hhi, Hlo, t);
    }
}